// Round 1
// baseline (2885.864 us; speedup 1.0000x reference)
//
#include <hip/hip_runtime.h>
#include <hip/hip_bf16.h>

// Problem constants
#define B_    32
#define L_    200
#define H_    256
#define NH_   4
#define D_    64
#define C_    16
#define SCALE_ 0.125f
#define EPS_  1e-12f

struct ProjArgs {
  const float* X[9];
  const float* W[9];
  const float* Bi[9];
};

// ---------------------------------------------------------------------------
// Kernel 1: 9 projections  out = X @ W + bias, scattered into head-major
// Q[b][h][cq][l][d], K[b][h][ck][m][d], V[b][h][m][d]
// M=6400 rows, N=256, K=256.  64x64 tiles, 256 thr, 4x4 register tile.
// ---------------------------------------------------------------------------
__global__ __launch_bounds__(256) void proj_kernel(ProjArgs pa,
                                                   float* __restrict__ Qbuf,
                                                   float* __restrict__ Kbuf,
                                                   float* __restrict__ Vbuf) {
  const int z = blockIdx.z;
  const float* __restrict__ X    = pa.X[z];
  const float* __restrict__ W    = pa.W[z];
  const float* __restrict__ bias = pa.Bi[z];

  __shared__ float As[16][65];   // [k][m], padded (conflict-free writes/reads)
  __shared__ float Bs[16][64];   // [k][n]

  const int tid = threadIdx.x;
  const int tx = tid & 15, ty = tid >> 4;
  const int row0 = blockIdx.y * 64, col0 = blockIdx.x * 64;

  float acc[4][4] = {};

  for (int k0 = 0; k0 < 256; k0 += 16) {
    for (int i = tid; i < 1024; i += 256) {
      int m = i >> 4, k = i & 15;
      As[k][m] = X[(row0 + m) * 256 + k0 + k];
    }
    for (int i = tid; i < 1024; i += 256) {
      int k = i >> 6, n = i & 63;
      Bs[k][n] = W[(k0 + k) * 256 + col0 + n];
    }
    __syncthreads();
#pragma unroll
    for (int k = 0; k < 16; ++k) {
      float a0 = As[k][ty * 4 + 0];
      float a1 = As[k][ty * 4 + 1];
      float a2 = As[k][ty * 4 + 2];
      float a3 = As[k][ty * 4 + 3];
      float4 bv = *(const float4*)&Bs[k][tx * 4];
      acc[0][0] += a0 * bv.x; acc[0][1] += a0 * bv.y; acc[0][2] += a0 * bv.z; acc[0][3] += a0 * bv.w;
      acc[1][0] += a1 * bv.x; acc[1][1] += a1 * bv.y; acc[1][2] += a1 * bv.z; acc[1][3] += a1 * bv.w;
      acc[2][0] += a2 * bv.x; acc[2][1] += a2 * bv.y; acc[2][2] += a2 * bv.z; acc[2][3] += a2 * bv.w;
      acc[3][0] += a3 * bv.x; acc[3][1] += a3 * bv.y; acc[3][2] += a3 * bv.z; acc[3][3] += a3 * bv.w;
    }
    __syncthreads();
  }

#pragma unroll
  for (int i = 0; i < 4; ++i) {
    int r = row0 + ty * 4 + i;
    int b = r / 200, l = r % 200;
#pragma unroll
    for (int j = 0; j < 4; ++j) {
      int n = col0 + tx * 4 + j;
      float v = acc[i][j] + bias[n];
      int h = n >> 6, d = n & 63;
      if (z < 4)
        Qbuf[(((b * 4 + h) * 4 + z) * 200 + l) * 64 + d] = v;
      else if (z < 8)
        Kbuf[(((b * 4 + h) * 4 + (z - 4)) * 200 + l) * 64 + d] = v;
      else
        Vbuf[((b * 4 + h) * 200 + l) * 64 + d] = v;
    }
  }
}

// ---------------------------------------------------------------------------
// Kernel 2: fused attention core. One block per (b, h, l), 256 threads.
// Phases: q load -> scores ac[16][200] -> energy (ac@Wf1 relu @Wf2) ->
// softmax over 16 channels -> weighted scores + mask -> softmax over m ->
// probs @ V -> ctx.
// ---------------------------------------------------------------------------
__global__ __launch_bounds__(256) void attn_kernel(
    const float* __restrict__ Qbuf, const float* __restrict__ Kbuf,
    const float* __restrict__ Vbuf, const float* __restrict__ mask,
    const float* __restrict__ Wf1, const float* __restrict__ bf1,
    const float* __restrict__ Wf2, const float* __restrict__ bf2,
    float* __restrict__ Ctx) {
  const int l = blockIdx.x, h = blockIdx.y, b = blockIdx.z;
  const int tid = threadIdx.x;
  const int bh = b * 4 + h;

  __shared__ float q_sh[4][64];        // 1 KB
  __shared__ float acT[200 * 17];      // 13.6 KB, acT[m*17+c], c = cq*4+ck
  __shared__ float Wf1_sh[40 * 200];   // 32 KB
  __shared__ float part_sh[8][25][2];  // 1.6 KB
  __shared__ float w_sh[16];
  __shared__ float ps_sh[200];
  __shared__ float red_sh[4];
  __shared__ float ctxp[4][64];

  // phase 0: load q vectors (4 channels x 64)
  {
    int cq = tid >> 6, d = tid & 63;
    q_sh[cq][d] = Qbuf[((bh * 4 + cq) * 200 + l) * 64 + d];
  }
  __syncthreads();

  // phase 2: scores. thread (ck, ml) owns m = ml+64r, computes all 4 cq.
  {
    int ck = tid >> 6, ml = tid & 63;
    const float* Kb = Kbuf + (bh * 4 + ck) * 200 * 64;
    for (int r = 0; r < 4; ++r) {
      int m = ml + 64 * r;
      if (m < 200) {
        const float* Kr = Kb + m * 64;
        float s0 = 0.f, s1 = 0.f, s2 = 0.f, s3 = 0.f;
#pragma unroll
        for (int d4 = 0; d4 < 64; d4 += 4) {
          float4 kv = *(const float4*)(Kr + d4);
          float4 q0 = *(const float4*)&q_sh[0][d4];
          float4 q1 = *(const float4*)&q_sh[1][d4];
          float4 q2 = *(const float4*)&q_sh[2][d4];
          float4 q3 = *(const float4*)&q_sh[3][d4];
          s0 += q0.x * kv.x + q0.y * kv.y + q0.z * kv.z + q0.w * kv.w;
          s1 += q1.x * kv.x + q1.y * kv.y + q1.z * kv.z + q1.w * kv.w;
          s2 += q2.x * kv.x + q2.y * kv.y + q2.z * kv.z + q2.w * kv.w;
          s3 += q3.x * kv.x + q3.y * kv.y + q3.z * kv.z + q3.w * kv.w;
        }
        acT[m * 17 + 0 * 4 + ck] = s0;
        acT[m * 17 + 1 * 4 + ck] = s1;
        acT[m * 17 + 2 * 4 + ck] = s2;
        acT[m * 17 + 3 * 4 + ck] = s3;
      }
    }
  }

  // phase 3: energy[c] = sum_n relu( sum_m ac[c][m]*Wf1[m][n] + bf1[n] ) * Wf2[n]
  // thread (cp, ng): c in {2cp, 2cp+1}, n in {8ng..8ng+7}; 200 active threads.
  const int cp = tid / 25, ng = tid % 25;
  float acc0[8] = {0.f, 0.f, 0.f, 0.f, 0.f, 0.f, 0.f, 0.f};
  float acc1[8] = {0.f, 0.f, 0.f, 0.f, 0.f, 0.f, 0.f, 0.f};
  for (int t = 0; t < 5; ++t) {
    __syncthreads();  // prev-tile consumers done (also orders phase-2 writes at t=0)
    const int m0 = t * 40;
    for (int i = tid; i < 8000; i += 256) {
      Wf1_sh[i] = Wf1[m0 * 200 + i];
    }
    __syncthreads();
    if (tid < 200) {
#pragma unroll 4
      for (int mm = 0; mm < 40; ++mm) {
        float a0 = acT[(m0 + mm) * 17 + 2 * cp];
        float a1 = acT[(m0 + mm) * 17 + 2 * cp + 1];
        const float* wr = &Wf1_sh[mm * 200 + 8 * ng];
        float4 w0 = *(const float4*)wr;
        float4 w1 = *(const float4*)(wr + 4);
        acc0[0] += a0 * w0.x; acc0[1] += a0 * w0.y; acc0[2] += a0 * w0.z; acc0[3] += a0 * w0.w;
        acc0[4] += a0 * w1.x; acc0[5] += a0 * w1.y; acc0[6] += a0 * w1.z; acc0[7] += a0 * w1.w;
        acc1[0] += a1 * w0.x; acc1[1] += a1 * w0.y; acc1[2] += a1 * w0.z; acc1[3] += a1 * w0.w;
        acc1[4] += a1 * w1.x; acc1[5] += a1 * w1.y; acc1[6] += a1 * w1.z; acc1[7] += a1 * w1.w;
      }
    }
  }
  if (tid < 200) {
    float e0 = 0.f, e1 = 0.f;
#pragma unroll
    for (int j = 0; j < 8; ++j) {
      int n = 8 * ng + j;
      float b1 = bf1[n], w2 = Wf2[n];
      e0 += fmaxf(acc0[j] + b1, 0.f) * w2;
      e1 += fmaxf(acc1[j] + b1, 0.f) * w2;
    }
    part_sh[cp][ng][0] = e0;
    part_sh[cp][ng][1] = e1;
  }
  __syncthreads();

  // phase 4: channel softmax over 16 (lanes 0..15 of wave 0)
  if (tid < 16) {
    float e = bf2[0];
    for (int g = 0; g < 25; ++g) e += part_sh[tid >> 1][g][tid & 1];
    float mx = e;
#pragma unroll
    for (int o = 8; o; o >>= 1) mx = fmaxf(mx, __shfl_xor(mx, o));
    float ex = expf(e - mx);
    float s = ex;
#pragma unroll
    for (int o = 8; o; o >>= 1) s += __shfl_xor(s, o);
    w_sh[tid] = ex / s;
  }
  __syncthreads();

  // phase 5: attn row + masked softmax over m
  float pval = -3.0e38f;
  if (tid < 200) {
    float s = 0.f;
#pragma unroll
    for (int c = 0; c < 16; ++c) s += acT[tid * 17 + c] * w_sh[c];
    pval = s * SCALE_ + mask[l * 200 + tid];
  }
  float v = pval;
#pragma unroll
  for (int o = 32; o; o >>= 1) v = fmaxf(v, __shfl_xor(v, o));
  if ((tid & 63) == 0) red_sh[tid >> 6] = v;
  __syncthreads();
  float mx = fmaxf(fmaxf(red_sh[0], red_sh[1]), fmaxf(red_sh[2], red_sh[3]));
  __syncthreads();
  float ex = (tid < 200) ? expf(pval - mx) : 0.f;
  v = ex;
#pragma unroll
  for (int o = 32; o; o >>= 1) v += __shfl_xor(v, o);
  if ((tid & 63) == 0) red_sh[tid >> 6] = v;
  __syncthreads();
  float sden = red_sh[0] + red_sh[1] + red_sh[2] + red_sh[3];
  if (tid < 200) ps_sh[tid] = ex / sden;
  __syncthreads();

  // phase 6: ctx[d] = sum_m probs[m] * V[m][d]
  {
    int d = tid & 63, rr = tid >> 6;
    const float* Vb = Vbuf + bh * 200 * 64;
    float s = 0.f;
    for (int m = rr * 50; m < rr * 50 + 50; ++m) s += ps_sh[m] * Vb[m * 64 + d];
    ctxp[rr][d] = s;
  }
  __syncthreads();
  if (tid < 64) {
    float c = ctxp[0][tid] + ctxp[1][tid] + ctxp[2][tid] + ctxp[3][tid];
    Ctx[(b * 200 + l) * 256 + h * 64 + tid] = c;
  }
}

// ---------------------------------------------------------------------------
// Kernel 3: x = ctx @ Wd + bd + input; LayerNorm(x). One block per row.
// ---------------------------------------------------------------------------
__global__ __launch_bounds__(256) void out_ln_kernel(
    const float* __restrict__ Ctx, const float* __restrict__ Wd,
    const float* __restrict__ bd, const float* __restrict__ input,
    const float* __restrict__ gamma, const float* __restrict__ beta,
    float* __restrict__ out) {
  const int row = blockIdx.x;
  const int n = threadIdx.x;
  __shared__ float c_sh[256];
  __shared__ float red[4];

  c_sh[n] = Ctx[row * 256 + n];
  __syncthreads();

  float acc = bd[n];
#pragma unroll 8
  for (int k = 0; k < 256; ++k) acc += c_sh[k] * Wd[k * 256 + n];
  float x = acc + input[row * 256 + n];

  float s = x;
#pragma unroll
  for (int o = 32; o; o >>= 1) s += __shfl_xor(s, o);
  if ((n & 63) == 0) red[n >> 6] = s;
  __syncthreads();
  float mu = (red[0] + red[1] + red[2] + red[3]) * (1.f / 256.f);
  __syncthreads();
  float dv = (x - mu) * (x - mu);
#pragma unroll
  for (int o = 32; o; o >>= 1) dv += __shfl_xor(dv, o);
  if ((n & 63) == 0) red[n >> 6] = dv;
  __syncthreads();
  float var = (red[0] + red[1] + red[2] + red[3]) * (1.f / 256.f);

  out[row * 256 + n] = (x - mu) * rsqrtf(var + EPS_) * gamma[n] + beta[n];
}

// ---------------------------------------------------------------------------
extern "C" void kernel_launch(void* const* d_in, const int* in_sizes, int n_in,
                              void* d_out, int out_size, void* d_ws, size_t ws_size,
                              hipStream_t stream) {
  const float* input = (const float*)d_in[0];
  const float* attrt = (const float*)d_in[1];   // (F,B,L,1,H)
  const float* pos   = (const float*)d_in[2];
  const float* mask  = (const float*)d_in[3];
  const float* Wq  = (const float*)d_in[4];   const float* bq  = (const float*)d_in[5];
  const float* Wk  = (const float*)d_in[6];   const float* bk  = (const float*)d_in[7];
  const float* Wv  = (const float*)d_in[8];   const float* bv  = (const float*)d_in[9];
  const float* Wqp = (const float*)d_in[10];  const float* bqp = (const float*)d_in[11];
  const float* Wkp = (const float*)d_in[12];  const float* bkp = (const float*)d_in[13];
  // d_in[14], d_in[15] = Wvp, bvp (unused by the reference forward)
  const float* Wq_a = (const float*)d_in[16]; const float* bq_a = (const float*)d_in[17];
  const float* Wk_a = (const float*)d_in[18]; const float* bk_a = (const float*)d_in[19];
  // d_in[20], d_in[21] = Wv_a, bv_a (unused)
  const float* Wf1 = (const float*)d_in[22];  const float* bf1 = (const float*)d_in[23];
  const float* Wf2 = (const float*)d_in[24];  const float* bf2 = (const float*)d_in[25];
  const float* Wd  = (const float*)d_in[26];  const float* bd  = (const float*)d_in[27];
  const float* gamma = (const float*)d_in[28]; const float* beta = (const float*)d_in[29];

  const float* attr0 = attrt;                        // (B,L,H)
  const float* attr1 = attrt + (size_t)B_ * L_ * H_;

  float* ws = (float*)d_ws;
  float* Qbuf = ws;                       // B*NH*4*L*D = 6,553,600 floats
  float* Kbuf = Qbuf + 6553600;           // 6,553,600
  float* Vbuf = Kbuf + 6553600;           // 1,638,400
  float* Ctx  = Vbuf + 1638400;           // 1,638,400   (total 62.5 MiB)

  ProjArgs pa;
  // Q channels: 0=q_i, 1=q_p, 2=q_a0, 3=q_a1
  pa.X[0] = input; pa.W[0] = Wq;              pa.Bi[0] = bq;
  pa.X[1] = pos;   pa.W[1] = Wqp;             pa.Bi[1] = bqp;
  pa.X[2] = attr0; pa.W[2] = Wq_a;            pa.Bi[2] = bq_a;
  pa.X[3] = attr1; pa.W[3] = Wq_a + 65536;    pa.Bi[3] = bq_a + 256;
  // K channels: 0=k_i, 1=k_a0, 2=k_a1, 3=k_p
  pa.X[4] = input; pa.W[4] = Wk;              pa.Bi[4] = bk;
  pa.X[5] = attr0; pa.W[5] = Wk_a;            pa.Bi[5] = bk_a;
  pa.X[6] = attr1; pa.W[6] = Wk_a + 65536;    pa.Bi[6] = bk_a + 256;
  pa.X[7] = pos;   pa.W[7] = Wkp;             pa.Bi[7] = bkp;
  // V
  pa.X[8] = input; pa.W[8] = Wv;              pa.Bi[8] = bv;

  proj_kernel<<<dim3(4, 100, 9), dim3(256), 0, stream>>>(pa, Qbuf, Kbuf, Vbuf);
  attn_kernel<<<dim3(200, 4, 32), dim3(256), 0, stream>>>(Qbuf, Kbuf, Vbuf, mask,
                                                          Wf1, bf1, Wf2, bf2, Ctx);
  out_ln_kernel<<<dim3(6400), dim3(256), 0, stream>>>(Ctx, Wd, bd, input,
                                                      gamma, beta, (float*)d_out);
}